// Round 9
// baseline (799.026 us; speedup 1.0000x reference)
//
#include <hip/hip_runtime.h>

#define IN_CH 16
#define HID 128
#define HEADS 4
#define NEG 0.2f
#define LN_EPS 1e-5f

__device__ __forceinline__ float bf2f(unsigned short u) {
  return __uint_as_float(((unsigned)u) << 16);
}
__device__ __forceinline__ unsigned short f2bf(float f) {
  unsigned u = __float_as_uint(f);
  unsigned r = (u + 0x7fffu + ((u >> 16) & 1u)) >> 16;  // RNE
  return (unsigned short)r;
}

// ---------------------------------------------------------------------------
// h1 = x @ W1 (N x 16 @ 16 x 128) -> bf16, fused per-head attention logits.
// ---------------------------------------------------------------------------
__global__ __launch_bounds__(128) void k_gemm1(
    const float* __restrict__ x, const float* __restrict__ W1,
    const float* __restrict__ a_src, const float* __restrict__ a_dst,
    unsigned short* __restrict__ hb, float* __restrict__ asrc,
    float* __restrict__ adst, int N) {
  int n = blockIdx.x;
  int c = threadIdx.x;
  __shared__ float xs[IN_CH];
  if (c < IN_CH) xs[c] = x[n * IN_CH + c];
  __syncthreads();
  float acc = 0.f;
#pragma unroll
  for (int k = 0; k < IN_CH; ++k) acc += xs[k] * W1[k * HID + c];
  hb[(size_t)n * HID + c] = f2bf(acc);
  float av = acc * a_src[c];
  float dv = acc * a_dst[c];
#pragma unroll
  for (int o = 16; o > 0; o >>= 1) {
    av += __shfl_down(av, o, 32);
    dv += __shfl_down(dv, o, 32);
  }
  if ((c & 31) == 0) {
    asrc[n * HEADS + (c >> 5)] = av;
    adst[n * HEADS + (c >> 5)] = dv;
  }
}

// ---------------------------------------------------------------------------
// CSR build: degree count
// ---------------------------------------------------------------------------
__global__ __launch_bounds__(256) void k_deg(
    const int* __restrict__ ei, int E, int Etot, int* __restrict__ deg) {
  int e = blockIdx.x * 256 + threadIdx.x;
  if (e >= Etot) return;
  int d = (e < E) ? ei[E + e] : (e - E);
  atomicAdd(&deg[d], 1);
}

__global__ __launch_bounds__(256) void k_scan1(
    const int* __restrict__ deg, int* __restrict__ part, int* __restrict__ aux,
    int N) {
  int i = blockIdx.x * 256 + threadIdx.x;
  int v = (i < N) ? deg[i] : 0;
  int lane = threadIdx.x & 63, w = threadIdx.x >> 6;
  int inc = v;
#pragma unroll
  for (int o = 1; o < 64; o <<= 1) {
    int t = __shfl_up(inc, o, 64);
    if (lane >= o) inc += t;
  }
  __shared__ int wsum[4];
  if (lane == 63) wsum[w] = inc;
  __syncthreads();
  int woff = 0;
#pragma unroll
  for (int k = 0; k < 4; ++k)
    if (k < w) woff += wsum[k];
  if (i < N) part[i] = woff + inc - v;
  if (threadIdx.x == 255) aux[blockIdx.x] = woff + inc;
}

__global__ __launch_bounds__(512) void k_scan2(int* __restrict__ aux, int nb) {
  int i = threadIdx.x;
  int v = (i < nb) ? aux[i] : 0;
  int lane = i & 63, w = i >> 6;
  int inc = v;
#pragma unroll
  for (int o = 1; o < 64; o <<= 1) {
    int t = __shfl_up(inc, o, 64);
    if (lane >= o) inc += t;
  }
  __shared__ int wsum[8];
  if (lane == 63) wsum[w] = inc;
  __syncthreads();
  int woff = 0;
#pragma unroll
  for (int k = 0; k < 8; ++k)
    if (k < w) woff += wsum[k];
  if (i < nb) aux[i] = woff + inc - v;
}

__global__ __launch_bounds__(256) void k_scan3(
    const int* __restrict__ part, const int* __restrict__ aux,
    int* __restrict__ rowstart, int* __restrict__ cursor, int N, int Etot) {
  int i = blockIdx.x * 256 + threadIdx.x;
  if (i < N) {
    int r = part[i] + aux[blockIdx.x];
    rowstart[i] = r;
    cursor[i] = r;
  }
  if (i == 0) rowstart[N] = Etot;
}

// ---------------------------------------------------------------------------
// CSR scatter, XCD-partitioned (R5-verified).
// ---------------------------------------------------------------------------
__global__ __launch_bounds__(256) void k_scatter(
    const int* __restrict__ ei, int E, int Etot, int* __restrict__ cursor,
    int* __restrict__ csr_src) {
  int cls = blockIdx.x & 7;
  int blk = blockIdx.x >> 3;
  int nblk = gridDim.x >> 3;
  for (int e = blk * 256 + threadIdx.x; e < Etot; e += nblk * 256) {
    int d = (e < E) ? ei[E + e] : (e - E);
    if (((d >> 6) & 7) != cls) continue;
    int s = (e < E) ? ei[e] : d;
    int pos = atomicAdd(&cursor[d], 1);
    csr_src[pos] = s;
  }
}

// ---------------------------------------------------------------------------
// Degree-balance permutation: bucket nodes by degree (64 bins).
// ---------------------------------------------------------------------------
__global__ __launch_bounds__(256) void k_dhist(
    const int* __restrict__ deg, int* __restrict__ dhist, int N) {
  __shared__ int lh[64];
  int t = threadIdx.x;
  if (t < 64) lh[t] = 0;
  __syncthreads();
  int i = blockIdx.x * 256 + t;
  if (i < N) atomicAdd(&lh[min(deg[i], 63)], 1);
  __syncthreads();
  if (t < 64 && lh[t]) atomicAdd(&dhist[t], lh[t]);
}

__global__ __launch_bounds__(64) void k_dscan(
    const int* __restrict__ dhist, int* __restrict__ dcur) {
  int l = threadIdx.x;
  int v = dhist[l];
  int inc = v;
#pragma unroll
  for (int o = 1; o < 64; o <<= 1) {
    int u = __shfl_up(inc, o, 64);
    if (l >= o) inc += u;
  }
  dcur[l] = inc - v;
}

__global__ __launch_bounds__(256) void k_dperm(
    const int* __restrict__ deg, int* __restrict__ dcur,
    int* __restrict__ perm, int N) {
  int i = blockIdx.x * 256 + threadIdx.x;
  if (i >= N) return;
  int p = atomicAdd(&dcur[min(deg[i], 63)], 1);
  perm[p] = i;
}

// ---------------------------------------------------------------------------
// Fused GAT agg + bias + ELU + LN, layer 1 (4 heads). bf16 gather payload,
// degree-balanced node order, bf16 x2 output. 32 threads/node, 8 nodes/block.
// ---------------------------------------------------------------------------
__global__ __launch_bounds__(256) void k_agg1(
    const int* __restrict__ perm, const int* __restrict__ rowstart,
    const int* __restrict__ csr_src, const float* __restrict__ asrc,
    const float* __restrict__ adst, const unsigned short* __restrict__ hb,
    const float* __restrict__ bias, const float* __restrict__ g,
    const float* __restrict__ beta, unsigned short* __restrict__ outb, int N) {
  int idx = blockIdx.x * 8 + (threadIdx.x >> 5);
  if (idx >= N) return;
  int d = perm[idx];
  int lane = threadIdx.x & 31;
  int c0 = lane << 2;
  int hd = lane >> 3;
  float ad = adst[d * HEADS + hd];
  int beg = rowstart[d], end = rowstart[d + 1];
  float a0 = 0.f, a1 = 0.f, a2 = 0.f, a3 = 0.f, wsum = 0.f;
  int i = beg;
  for (; i + 4 <= end; i += 4) {
    int sA = csr_src[i], sB = csr_src[i + 1];
    int sC = csr_src[i + 2], sD = csr_src[i + 3];
    float vA = asrc[sA * HEADS + hd] + ad;
    float vB = asrc[sB * HEADS + hd] + ad;
    float vC = asrc[sC * HEADS + hd] + ad;
    float vD = asrc[sD * HEADS + hd] + ad;
    ushort4 pA = *(const ushort4*)(hb + (size_t)sA * HID + c0);
    ushort4 pB = *(const ushort4*)(hb + (size_t)sB * HID + c0);
    ushort4 pC = *(const ushort4*)(hb + (size_t)sC * HID + c0);
    ushort4 pD = *(const ushort4*)(hb + (size_t)sD * HID + c0);
    vA = vA < 0.f ? NEG * vA : vA;
    vB = vB < 0.f ? NEG * vB : vB;
    vC = vC < 0.f ? NEG * vC : vC;
    vD = vD < 0.f ? NEG * vD : vD;
    float wA = __expf(vA), wB = __expf(vB);
    float wC = __expf(vC), wD = __expf(vD);
    wsum += (wA + wB) + (wC + wD);
    a0 += wA * bf2f(pA.x) + wB * bf2f(pB.x) + wC * bf2f(pC.x) + wD * bf2f(pD.x);
    a1 += wA * bf2f(pA.y) + wB * bf2f(pB.y) + wC * bf2f(pC.y) + wD * bf2f(pD.y);
    a2 += wA * bf2f(pA.z) + wB * bf2f(pB.z) + wC * bf2f(pC.z) + wD * bf2f(pD.z);
    a3 += wA * bf2f(pA.w) + wB * bf2f(pB.w) + wC * bf2f(pC.w) + wD * bf2f(pD.w);
  }
  for (; i < end; ++i) {
    int sA = csr_src[i];
    float vA = asrc[sA * HEADS + hd] + ad;
    ushort4 pA = *(const ushort4*)(hb + (size_t)sA * HID + c0);
    vA = vA < 0.f ? NEG * vA : vA;
    float wA = __expf(vA);
    wsum += wA;
    a0 += wA * bf2f(pA.x);
    a1 += wA * bf2f(pA.y);
    a2 += wA * bf2f(pA.z);
    a3 += wA * bf2f(pA.w);
  }
  float rw = 1.f / wsum;
  float v0 = a0 * rw + bias[c0 + 0];
  float v1 = a1 * rw + bias[c0 + 1];
  float v2 = a2 * rw + bias[c0 + 2];
  float v3 = a3 * rw + bias[c0 + 3];
  v0 = v0 > 0.f ? v0 : (__expf(v0) - 1.f);
  v1 = v1 > 0.f ? v1 : (__expf(v1) - 1.f);
  v2 = v2 > 0.f ? v2 : (__expf(v2) - 1.f);
  v3 = v3 > 0.f ? v3 : (__expf(v3) - 1.f);
  float s1 = v0 + v1 + v2 + v3;
  float s2 = v0 * v0 + v1 * v1 + v2 * v2 + v3 * v3;
#pragma unroll
  for (int o = 16; o > 0; o >>= 1) {
    s1 += __shfl_down(s1, o, 32);
    s2 += __shfl_down(s2, o, 32);
  }
  s1 = __shfl(s1, 0, 32);
  s2 = __shfl(s2, 0, 32);
  float mu = s1 * (1.f / HID);
  float var = s2 * (1.f / HID) - mu * mu;
  float inv = rsqrtf(var + LN_EPS);
  ushort4 o4;
  o4.x = f2bf((v0 - mu) * inv * g[c0 + 0] + beta[c0 + 0]);
  o4.y = f2bf((v1 - mu) * inv * g[c0 + 1] + beta[c0 + 1]);
  o4.z = f2bf((v2 - mu) * inv * g[c0 + 2] + beta[c0 + 2]);
  o4.w = f2bf((v3 - mu) * inv * g[c0 + 3] + beta[c0 + 3]);
  *(ushort4*)(outb + (size_t)d * HID + c0) = o4;
}

// ---------------------------------------------------------------------------
// Fused GAT agg + bias + ELU + LN, layer 2 (1 head). bf16 gather, f32 out.
// Degree-balanced node order.
// ---------------------------------------------------------------------------
__global__ __launch_bounds__(256) void k_agg2(
    const int* __restrict__ perm, const int* __restrict__ rowstart,
    const int* __restrict__ csr_src, const float* __restrict__ asrc,
    const float* __restrict__ adst, const unsigned short* __restrict__ hb,
    const float* __restrict__ bias, const float* __restrict__ g,
    const float* __restrict__ beta, float* __restrict__ out, int N) {
  int idx = blockIdx.x * 8 + (threadIdx.x >> 5);
  if (idx >= N) return;
  int d = perm[idx];
  int lane = threadIdx.x & 31;
  int c0 = lane << 2;
  float ad = adst[d];
  int beg = rowstart[d], end = rowstart[d + 1];
  float a0 = 0.f, a1 = 0.f, a2 = 0.f, a3 = 0.f, wsum = 0.f;
  int i = beg;
  for (; i + 4 <= end; i += 4) {
    int sA = csr_src[i], sB = csr_src[i + 1];
    int sC = csr_src[i + 2], sD = csr_src[i + 3];
    float vA = asrc[sA] + ad;
    float vB = asrc[sB] + ad;
    float vC = asrc[sC] + ad;
    float vD = asrc[sD] + ad;
    ushort4 pA = *(const ushort4*)(hb + (size_t)sA * HID + c0);
    ushort4 pB = *(const ushort4*)(hb + (size_t)sB * HID + c0);
    ushort4 pC = *(const ushort4*)(hb + (size_t)sC * HID + c0);
    ushort4 pD = *(const ushort4*)(hb + (size_t)sD * HID + c0);
    vA = vA < 0.f ? NEG * vA : vA;
    vB = vB < 0.f ? NEG * vB : vB;
    vC = vC < 0.f ? NEG * vC : vC;
    vD = vD < 0.f ? NEG * vD : vD;
    float wA = __expf(vA), wB = __expf(vB);
    float wC = __expf(vC), wD = __expf(vD);
    wsum += (wA + wB) + (wC + wD);
    a0 += wA * bf2f(pA.x) + wB * bf2f(pB.x) + wC * bf2f(pC.x) + wD * bf2f(pD.x);
    a1 += wA * bf2f(pA.y) + wB * bf2f(pB.y) + wC * bf2f(pC.y) + wD * bf2f(pD.y);
    a2 += wA * bf2f(pA.z) + wB * bf2f(pB.z) + wC * bf2f(pC.z) + wD * bf2f(pD.z);
    a3 += wA * bf2f(pA.w) + wB * bf2f(pB.w) + wC * bf2f(pC.w) + wD * bf2f(pD.w);
  }
  for (; i < end; ++i) {
    int sA = csr_src[i];
    float vA = asrc[sA] + ad;
    ushort4 pA = *(const ushort4*)(hb + (size_t)sA * HID + c0);
    vA = vA < 0.f ? NEG * vA : vA;
    float wA = __expf(vA);
    wsum += wA;
    a0 += wA * bf2f(pA.x);
    a1 += wA * bf2f(pA.y);
    a2 += wA * bf2f(pA.z);
    a3 += wA * bf2f(pA.w);
  }
  float rw = 1.f / wsum;
  float v0 = a0 * rw + bias[c0 + 0];
  float v1 = a1 * rw + bias[c0 + 1];
  float v2 = a2 * rw + bias[c0 + 2];
  float v3 = a3 * rw + bias[c0 + 3];
  v0 = v0 > 0.f ? v0 : (__expf(v0) - 1.f);
  v1 = v1 > 0.f ? v1 : (__expf(v1) - 1.f);
  v2 = v2 > 0.f ? v2 : (__expf(v2) - 1.f);
  v3 = v3 > 0.f ? v3 : (__expf(v3) - 1.f);
  float s1 = v0 + v1 + v2 + v3;
  float s2 = v0 * v0 + v1 * v1 + v2 * v2 + v3 * v3;
#pragma unroll
  for (int o = 16; o > 0; o >>= 1) {
    s1 += __shfl_down(s1, o, 32);
    s2 += __shfl_down(s2, o, 32);
  }
  s1 = __shfl(s1, 0, 32);
  s2 = __shfl(s2, 0, 32);
  float mu = s1 * (1.f / HID);
  float var = s2 * (1.f / HID) - mu * mu;
  float inv = rsqrtf(var + LN_EPS);
  float4 o4;
  o4.x = (v0 - mu) * inv * g[c0 + 0] + beta[c0 + 0];
  o4.y = (v1 - mu) * inv * g[c0 + 1] + beta[c0 + 1];
  o4.z = (v2 - mu) * inv * g[c0 + 2] + beta[c0 + 2];
  o4.w = (v3 - mu) * inv * g[c0 + 3] + beta[c0 + 3];
  *(float4*)(out + (size_t)d * HID + c0) = o4;
}

// ---------------------------------------------------------------------------
// h2 = x2 @ W2 (N x 128 @ 128 x 128), VALU f32 accumulate.
// bf16 x2 in, bf16 h2 out, fused alpha2 logits. (R7-verified)
// ---------------------------------------------------------------------------
__global__ __launch_bounds__(256) void k_gemm2f(
    const unsigned short* __restrict__ x2b, const float* __restrict__ W2,
    const float* __restrict__ a_src, const float* __restrict__ a_dst,
    unsigned short* __restrict__ h2b, float* __restrict__ asrc,
    float* __restrict__ adst, int N) {
  __shared__ float xs[32][HID];
  int nb = blockIdx.x * 32;
  int t = threadIdx.x;
  for (int i = t; i < 512; i += 256) {
    int row = i >> 4;
    int c8 = i & 15;
    int node = nb + row;
    uint4 v = make_uint4(0u, 0u, 0u, 0u);
    if (node < N) v = ((const uint4*)(x2b + (size_t)node * HID))[c8];
    const unsigned short* sp = (const unsigned short*)&v;
    float* dst = &xs[row][c8 * 8];
#pragma unroll
    for (int j = 0; j < 8; ++j) dst[j] = bf2f(sp[j]);
  }
  __syncthreads();
  int lane = t & 63;
  int col0 = lane * 2;
  int ng = t >> 6;
  float acc[8][2] = {};
  for (int k = 0; k < HID; k += 4) {
    float2 w0 = *(const float2*)(W2 + (size_t)(k + 0) * HID + col0);
    float2 w1 = *(const float2*)(W2 + (size_t)(k + 1) * HID + col0);
    float2 w2 = *(const float2*)(W2 + (size_t)(k + 2) * HID + col0);
    float2 w3 = *(const float2*)(W2 + (size_t)(k + 3) * HID + col0);
#pragma unroll
    for (int nd = 0; nd < 8; ++nd) {
      float4 xv = *(const float4*)(&xs[ng * 8 + nd][k]);
      acc[nd][0] += xv.x * w0.x + xv.y * w1.x + xv.z * w2.x + xv.w * w3.x;
      acc[nd][1] += xv.x * w0.y + xv.y * w1.y + xv.z * w2.y + xv.w * w3.y;
    }
  }
  float s0 = a_src[col0], s1 = a_src[col0 + 1];
  float d0 = a_dst[col0], d1 = a_dst[col0 + 1];
#pragma unroll
  for (int nd = 0; nd < 8; ++nd) {
    int n = nb + ng * 8 + nd;
    float av = acc[nd][0] * s0 + acc[nd][1] * s1;
    float dv = acc[nd][0] * d0 + acc[nd][1] * d1;
#pragma unroll
    for (int o = 32; o > 0; o >>= 1) {
      av += __shfl_down(av, o, 64);
      dv += __shfl_down(dv, o, 64);
    }
    if (n < N) {
      ushort2 ob;
      ob.x = f2bf(acc[nd][0]);
      ob.y = f2bf(acc[nd][1]);
      *(ushort2*)(h2b + (size_t)n * HID + col0) = ob;
      if (lane == 0) {
        asrc[n] = av;
        adst[n] = dv;
      }
    }
  }
}

extern "C" void kernel_launch(void* const* d_in, const int* in_sizes, int n_in,
                              void* d_out, int out_size, void* d_ws, size_t ws_size,
                              hipStream_t stream) {
  const float* x      = (const float*)d_in[0];
  const int*   ei     = (const int*)d_in[1];
  const float* W1     = (const float*)d_in[2];
  const float* a_src1 = (const float*)d_in[3];
  const float* a_dst1 = (const float*)d_in[4];
  const float* b1     = (const float*)d_in[5];
  const float* g1     = (const float*)d_in[6];
  const float* beta1  = (const float*)d_in[7];
  const float* W2     = (const float*)d_in[8];
  const float* a_src2 = (const float*)d_in[9];
  const float* a_dst2 = (const float*)d_in[10];
  const float* b2     = (const float*)d_in[11];
  const float* g2     = (const float*)d_in[12];
  const float* beta2  = (const float*)d_in[13];
  float* out = (float*)d_out;

  const int N = in_sizes[0] / IN_CH;
  const int E = in_sizes[1] / 2;
  const int Etot = E + N;
  const int nblk = (N + 255) / 256;

  // workspace layout
  unsigned short* hb  = (unsigned short*)d_ws;          // h1 bf16 -> h2 bf16
  unsigned short* x2b = hb + (size_t)N * HID;           // x2 bf16
  float* asrc1 = (float*)(x2b + (size_t)N * HID);
  float* adst1 = asrc1 + (size_t)N * HEADS;
  float* asrc2 = adst1 + (size_t)N * HEADS;
  float* adst2 = asrc2 + N;
  int* deg      = (int*)(adst2 + N);
  int* part     = deg + N;
  int* rowstart = part + N;           // [N+1]
  int* cursor   = rowstart + N + 1;
  int* aux      = cursor + N;         // [<=1024]
  int* perm     = aux + 1024;         // [N]
  int* dhist    = perm + N;           // [64]
  int* dcur     = dhist + 64;         // [64]
  int* csr_src  = dcur + 64;          // [Etot]

  // ---- CSR build + degree-balance permutation ----
  hipMemsetAsync(deg, 0, (size_t)N * sizeof(int), stream);
  hipMemsetAsync(dhist, 0, 64 * sizeof(int), stream);
  k_deg<<<(Etot + 255) / 256, 256, 0, stream>>>(ei, E, Etot, deg);
  k_scan1<<<nblk, 256, 0, stream>>>(deg, part, aux, N);
  k_scan2<<<1, 512, 0, stream>>>(aux, nblk);
  k_scan3<<<nblk, 256, 0, stream>>>(part, aux, rowstart, cursor, N, Etot);
  k_scatter<<<3584, 256, 0, stream>>>(ei, E, Etot, cursor, csr_src);
  k_dhist<<<nblk, 256, 0, stream>>>(deg, dhist, N);
  k_dscan<<<1, 64, 0, stream>>>(dhist, dcur);
  k_dperm<<<nblk, 256, 0, stream>>>(deg, dcur, perm, N);

  // ---- Layer 1 ----
  k_gemm1<<<N, 128, 0, stream>>>(x, W1, a_src1, a_dst1, hb, asrc1, adst1, N);
  k_agg1<<<(N + 7) / 8, 256, 0, stream>>>(perm, rowstart, csr_src, asrc1, adst1,
                                          hb, b1, g1, beta1, x2b, N);

  // ---- Layer 2 ----  (h2 bf16 reuses hb; h1 dead after agg1)
  k_gemm2f<<<(N + 31) / 32, 256, 0, stream>>>(x2b, W2, a_src2, a_dst2,
                                              hb, asrc2, adst2, N);
  k_agg2<<<(N + 7) / 8, 256, 0, stream>>>(perm, rowstart, csr_src, asrc2, adst2,
                                          hb, b2, g2, beta2, out, N);
}

// Round 10
// 482.123 us; speedup vs baseline: 1.6573x; 1.6573x over previous
//
#include <hip/hip_runtime.h>

#define IN_CH 16
#define HID 128
#define HEADS 4
#define NEG 0.2f
#define LN_EPS 1e-5f

__device__ __forceinline__ float bf2f(unsigned short u) {
  return __uint_as_float(((unsigned)u) << 16);
}
__device__ __forceinline__ unsigned short f2bf(float f) {
  unsigned u = __float_as_uint(f);
  unsigned r = (u + 0x7fffu + ((u >> 16) & 1u)) >> 16;  // RNE
  return (unsigned short)r;
}

// ---------------------------------------------------------------------------
// h1 = x @ W1 (N x 16 @ 16 x 128) -> bf16, fused per-head attention logits.
// ---------------------------------------------------------------------------
__global__ __launch_bounds__(128) void k_gemm1(
    const float* __restrict__ x, const float* __restrict__ W1,
    const float* __restrict__ a_src, const float* __restrict__ a_dst,
    unsigned short* __restrict__ hb, float* __restrict__ asrc,
    float* __restrict__ adst, int N) {
  int n = blockIdx.x;
  int c = threadIdx.x;
  __shared__ float xs[IN_CH];
  if (c < IN_CH) xs[c] = x[n * IN_CH + c];
  __syncthreads();
  float acc = 0.f;
#pragma unroll
  for (int k = 0; k < IN_CH; ++k) acc += xs[k] * W1[k * HID + c];
  hb[(size_t)n * HID + c] = f2bf(acc);
  float av = acc * a_src[c];
  float dv = acc * a_dst[c];
#pragma unroll
  for (int o = 16; o > 0; o >>= 1) {
    av += __shfl_down(av, o, 32);
    dv += __shfl_down(dv, o, 32);
  }
  if ((c & 31) == 0) {
    asrc[n * HEADS + (c >> 5)] = av;
    adst[n * HEADS + (c >> 5)] = dv;
  }
}

// ---------------------------------------------------------------------------
// CSR build: degree count
// ---------------------------------------------------------------------------
__global__ __launch_bounds__(256) void k_deg(
    const int* __restrict__ ei, int E, int Etot, int* __restrict__ deg) {
  int e = blockIdx.x * 256 + threadIdx.x;
  if (e >= Etot) return;
  int d = (e < E) ? ei[E + e] : (e - E);
  atomicAdd(&deg[d], 1);
}

__global__ __launch_bounds__(256) void k_scan1(
    const int* __restrict__ deg, int* __restrict__ part, int* __restrict__ aux,
    int N) {
  int i = blockIdx.x * 256 + threadIdx.x;
  int v = (i < N) ? deg[i] : 0;
  int lane = threadIdx.x & 63, w = threadIdx.x >> 6;
  int inc = v;
#pragma unroll
  for (int o = 1; o < 64; o <<= 1) {
    int t = __shfl_up(inc, o, 64);
    if (lane >= o) inc += t;
  }
  __shared__ int wsum[4];
  if (lane == 63) wsum[w] = inc;
  __syncthreads();
  int woff = 0;
#pragma unroll
  for (int k = 0; k < 4; ++k)
    if (k < w) woff += wsum[k];
  if (i < N) part[i] = woff + inc - v;
  if (threadIdx.x == 255) aux[blockIdx.x] = woff + inc;
}

__global__ __launch_bounds__(512) void k_scan2(int* __restrict__ aux, int nb) {
  int i = threadIdx.x;
  int v = (i < nb) ? aux[i] : 0;
  int lane = i & 63, w = i >> 6;
  int inc = v;
#pragma unroll
  for (int o = 1; o < 64; o <<= 1) {
    int t = __shfl_up(inc, o, 64);
    if (lane >= o) inc += t;
  }
  __shared__ int wsum[8];
  if (lane == 63) wsum[w] = inc;
  __syncthreads();
  int woff = 0;
#pragma unroll
  for (int k = 0; k < 8; ++k)
    if (k < w) woff += wsum[k];
  if (i < nb) aux[i] = woff + inc - v;
}

__global__ __launch_bounds__(256) void k_scan3(
    const int* __restrict__ part, const int* __restrict__ aux,
    int* __restrict__ rowstart, int* __restrict__ cursor, int N, int Etot) {
  int i = blockIdx.x * 256 + threadIdx.x;
  if (i < N) {
    int r = part[i] + aux[blockIdx.x];
    rowstart[i] = r;
    cursor[i] = r;
  }
  if (i == 0) rowstart[N] = Etot;
}

// ---------------------------------------------------------------------------
// CSR scatter, XCD-partitioned (R5-verified).
// ---------------------------------------------------------------------------
__global__ __launch_bounds__(256) void k_scatter(
    const int* __restrict__ ei, int E, int Etot, int* __restrict__ cursor,
    int* __restrict__ csr_src) {
  int cls = blockIdx.x & 7;
  int blk = blockIdx.x >> 3;
  int nblk = gridDim.x >> 3;
  for (int e = blk * 256 + threadIdx.x; e < Etot; e += nblk * 256) {
    int d = (e < E) ? ei[E + e] : (e - E);
    if (((d >> 6) & 7) != cls) continue;
    int s = (e < E) ? ei[e] : d;
    int pos = atomicAdd(&cursor[d], 1);
    csr_src[pos] = s;
  }
}

// ---------------------------------------------------------------------------
// Fused GAT agg + bias + ELU + LN, layer 1 (4 heads). bf16 gather payload,
// bf16 x2 output. 32 threads/node, 8 nodes/block. (R7-verified)
// ---------------------------------------------------------------------------
__global__ __launch_bounds__(256) void k_agg1(
    const int* __restrict__ rowstart, const int* __restrict__ csr_src,
    const float* __restrict__ asrc, const float* __restrict__ adst,
    const unsigned short* __restrict__ hb, const float* __restrict__ bias,
    const float* __restrict__ g, const float* __restrict__ beta,
    unsigned short* __restrict__ outb, int N) {
  int d = blockIdx.x * 8 + (threadIdx.x >> 5);
  if (d >= N) return;
  int lane = threadIdx.x & 31;
  int c0 = lane << 2;
  int hd = lane >> 3;
  float ad = adst[d * HEADS + hd];
  int beg = rowstart[d], end = rowstart[d + 1];
  float a0 = 0.f, a1 = 0.f, a2 = 0.f, a3 = 0.f, wsum = 0.f;
  int i = beg;
  for (; i + 4 <= end; i += 4) {
    int sA = csr_src[i], sB = csr_src[i + 1];
    int sC = csr_src[i + 2], sD = csr_src[i + 3];
    float vA = asrc[sA * HEADS + hd] + ad;
    float vB = asrc[sB * HEADS + hd] + ad;
    float vC = asrc[sC * HEADS + hd] + ad;
    float vD = asrc[sD * HEADS + hd] + ad;
    ushort4 pA = *(const ushort4*)(hb + (size_t)sA * HID + c0);
    ushort4 pB = *(const ushort4*)(hb + (size_t)sB * HID + c0);
    ushort4 pC = *(const ushort4*)(hb + (size_t)sC * HID + c0);
    ushort4 pD = *(const ushort4*)(hb + (size_t)sD * HID + c0);
    vA = vA < 0.f ? NEG * vA : vA;
    vB = vB < 0.f ? NEG * vB : vB;
    vC = vC < 0.f ? NEG * vC : vC;
    vD = vD < 0.f ? NEG * vD : vD;
    float wA = __expf(vA), wB = __expf(vB);
    float wC = __expf(vC), wD = __expf(vD);
    wsum += (wA + wB) + (wC + wD);
    a0 += wA * bf2f(pA.x) + wB * bf2f(pB.x) + wC * bf2f(pC.x) + wD * bf2f(pD.x);
    a1 += wA * bf2f(pA.y) + wB * bf2f(pB.y) + wC * bf2f(pC.y) + wD * bf2f(pD.y);
    a2 += wA * bf2f(pA.z) + wB * bf2f(pB.z) + wC * bf2f(pC.z) + wD * bf2f(pD.z);
    a3 += wA * bf2f(pA.w) + wB * bf2f(pB.w) + wC * bf2f(pC.w) + wD * bf2f(pD.w);
  }
  for (; i < end; ++i) {
    int sA = csr_src[i];
    float vA = asrc[sA * HEADS + hd] + ad;
    ushort4 pA = *(const ushort4*)(hb + (size_t)sA * HID + c0);
    vA = vA < 0.f ? NEG * vA : vA;
    float wA = __expf(vA);
    wsum += wA;
    a0 += wA * bf2f(pA.x);
    a1 += wA * bf2f(pA.y);
    a2 += wA * bf2f(pA.z);
    a3 += wA * bf2f(pA.w);
  }
  float rw = 1.f / wsum;
  float v0 = a0 * rw + bias[c0 + 0];
  float v1 = a1 * rw + bias[c0 + 1];
  float v2 = a2 * rw + bias[c0 + 2];
  float v3 = a3 * rw + bias[c0 + 3];
  v0 = v0 > 0.f ? v0 : (__expf(v0) - 1.f);
  v1 = v1 > 0.f ? v1 : (__expf(v1) - 1.f);
  v2 = v2 > 0.f ? v2 : (__expf(v2) - 1.f);
  v3 = v3 > 0.f ? v3 : (__expf(v3) - 1.f);
  float s1 = v0 + v1 + v2 + v3;
  float s2 = v0 * v0 + v1 * v1 + v2 * v2 + v3 * v3;
#pragma unroll
  for (int o = 16; o > 0; o >>= 1) {
    s1 += __shfl_down(s1, o, 32);
    s2 += __shfl_down(s2, o, 32);
  }
  s1 = __shfl(s1, 0, 32);
  s2 = __shfl(s2, 0, 32);
  float mu = s1 * (1.f / HID);
  float var = s2 * (1.f / HID) - mu * mu;
  float inv = rsqrtf(var + LN_EPS);
  ushort4 o4;
  o4.x = f2bf((v0 - mu) * inv * g[c0 + 0] + beta[c0 + 0]);
  o4.y = f2bf((v1 - mu) * inv * g[c0 + 1] + beta[c0 + 1]);
  o4.z = f2bf((v2 - mu) * inv * g[c0 + 2] + beta[c0 + 2]);
  o4.w = f2bf((v3 - mu) * inv * g[c0 + 3] + beta[c0 + 3]);
  *(ushort4*)(outb + (size_t)d * HID + c0) = o4;
}

// ---------------------------------------------------------------------------
// Fused GAT agg + bias + ELU + LN, layer 2 (1 head). bf16 gather, f32 out.
// (R7-verified)
// ---------------------------------------------------------------------------
__global__ __launch_bounds__(256) void k_agg2(
    const int* __restrict__ rowstart, const int* __restrict__ csr_src,
    const float* __restrict__ asrc, const float* __restrict__ adst,
    const unsigned short* __restrict__ hb, const float* __restrict__ bias,
    const float* __restrict__ g, const float* __restrict__ beta,
    float* __restrict__ out, int N) {
  int d = blockIdx.x * 8 + (threadIdx.x >> 5);
  if (d >= N) return;
  int lane = threadIdx.x & 31;
  int c0 = lane << 2;
  float ad = adst[d];
  int beg = rowstart[d], end = rowstart[d + 1];
  float a0 = 0.f, a1 = 0.f, a2 = 0.f, a3 = 0.f, wsum = 0.f;
  int i = beg;
  for (; i + 4 <= end; i += 4) {
    int sA = csr_src[i], sB = csr_src[i + 1];
    int sC = csr_src[i + 2], sD = csr_src[i + 3];
    float vA = asrc[sA] + ad;
    float vB = asrc[sB] + ad;
    float vC = asrc[sC] + ad;
    float vD = asrc[sD] + ad;
    ushort4 pA = *(const ushort4*)(hb + (size_t)sA * HID + c0);
    ushort4 pB = *(const ushort4*)(hb + (size_t)sB * HID + c0);
    ushort4 pC = *(const ushort4*)(hb + (size_t)sC * HID + c0);
    ushort4 pD = *(const ushort4*)(hb + (size_t)sD * HID + c0);
    vA = vA < 0.f ? NEG * vA : vA;
    vB = vB < 0.f ? NEG * vB : vB;
    vC = vC < 0.f ? NEG * vC : vC;
    vD = vD < 0.f ? NEG * vD : vD;
    float wA = __expf(vA), wB = __expf(vB);
    float wC = __expf(vC), wD = __expf(vD);
    wsum += (wA + wB) + (wC + wD);
    a0 += wA * bf2f(pA.x) + wB * bf2f(pB.x) + wC * bf2f(pC.x) + wD * bf2f(pD.x);
    a1 += wA * bf2f(pA.y) + wB * bf2f(pB.y) + wC * bf2f(pC.y) + wD * bf2f(pD.y);
    a2 += wA * bf2f(pA.z) + wB * bf2f(pB.z) + wC * bf2f(pC.z) + wD * bf2f(pD.z);
    a3 += wA * bf2f(pA.w) + wB * bf2f(pB.w) + wC * bf2f(pC.w) + wD * bf2f(pD.w);
  }
  for (; i < end; ++i) {
    int sA = csr_src[i];
    float vA = asrc[sA] + ad;
    ushort4 pA = *(const ushort4*)(hb + (size_t)sA * HID + c0);
    vA = vA < 0.f ? NEG * vA : vA;
    float wA = __expf(vA);
    wsum += wA;
    a0 += wA * bf2f(pA.x);
    a1 += wA * bf2f(pA.y);
    a2 += wA * bf2f(pA.z);
    a3 += wA * bf2f(pA.w);
  }
  float rw = 1.f / wsum;
  float v0 = a0 * rw + bias[c0 + 0];
  float v1 = a1 * rw + bias[c0 + 1];
  float v2 = a2 * rw + bias[c0 + 2];
  float v3 = a3 * rw + bias[c0 + 3];
  v0 = v0 > 0.f ? v0 : (__expf(v0) - 1.f);
  v1 = v1 > 0.f ? v1 : (__expf(v1) - 1.f);
  v2 = v2 > 0.f ? v2 : (__expf(v2) - 1.f);
  v3 = v3 > 0.f ? v3 : (__expf(v3) - 1.f);
  float s1 = v0 + v1 + v2 + v3;
  float s2 = v0 * v0 + v1 * v1 + v2 * v2 + v3 * v3;
#pragma unroll
  for (int o = 16; o > 0; o >>= 1) {
    s1 += __shfl_down(s1, o, 32);
    s2 += __shfl_down(s2, o, 32);
  }
  s1 = __shfl(s1, 0, 32);
  s2 = __shfl(s2, 0, 32);
  float mu = s1 * (1.f / HID);
  float var = s2 * (1.f / HID) - mu * mu;
  float inv = rsqrtf(var + LN_EPS);
  float4 o4;
  o4.x = (v0 - mu) * inv * g[c0 + 0] + beta[c0 + 0];
  o4.y = (v1 - mu) * inv * g[c0 + 1] + beta[c0 + 1];
  o4.z = (v2 - mu) * inv * g[c0 + 2] + beta[c0 + 2];
  o4.w = (v3 - mu) * inv * g[c0 + 3] + beta[c0 + 3];
  *(float4*)(out + (size_t)d * HID + c0) = o4;
}

// ---------------------------------------------------------------------------
// h2 = x2 @ W2 (N x 128 @ 128 x 128), VALU f32 accumulate.
// bf16 x2 in, bf16 h2 out, fused alpha2 logits.
// Remapped: thread = 4 cols (float4 W2 loads) x 4 nodes; half-wave (32-lane)
// owns all 128 cols of 4 nodes. Per-col k-summation order identical to R7.
// ---------------------------------------------------------------------------
__global__ __launch_bounds__(256) void k_gemm2f(
    const unsigned short* __restrict__ x2b, const float* __restrict__ W2,
    const float* __restrict__ a_src, const float* __restrict__ a_dst,
    unsigned short* __restrict__ h2b, float* __restrict__ asrc,
    float* __restrict__ adst, int N) {
  __shared__ float xs[32][HID];
  int nb = blockIdx.x * 32;
  int t = threadIdx.x;
  for (int i = t; i < 512; i += 256) {
    int row = i >> 4;
    int c8 = i & 15;
    int node = nb + row;
    uint4 v = make_uint4(0u, 0u, 0u, 0u);
    if (node < N) v = ((const uint4*)(x2b + (size_t)node * HID))[c8];
    const unsigned short* sp = (const unsigned short*)&v;
    float* dst = &xs[row][c8 * 8];
#pragma unroll
    for (int j = 0; j < 8; ++j) dst[j] = bf2f(sp[j]);
  }
  __syncthreads();
  int lane = t & 63;
  int half = lane >> 5;            // 0 or 1
  int c4 = (lane & 31) * 4;        // 4 cols c4..c4+3
  int ng = t >> 6;                 // wave id: nodes ng*8 + half*4 + {0..3}
  int nrow0 = ng * 8 + half * 4;
  float acc[4][4] = {};
  for (int k = 0; k < HID; k += 4) {
    float4 w0 = *(const float4*)(W2 + (size_t)(k + 0) * HID + c4);
    float4 w1 = *(const float4*)(W2 + (size_t)(k + 1) * HID + c4);
    float4 w2 = *(const float4*)(W2 + (size_t)(k + 2) * HID + c4);
    float4 w3 = *(const float4*)(W2 + (size_t)(k + 3) * HID + c4);
#pragma unroll
    for (int nd = 0; nd < 4; ++nd) {
      float4 xv = *(const float4*)(&xs[nrow0 + nd][k]);
      acc[nd][0] += xv.x * w0.x + xv.y * w1.x + xv.z * w2.x + xv.w * w3.x;
      acc[nd][1] += xv.x * w0.y + xv.y * w1.y + xv.z * w2.y + xv.w * w3.y;
      acc[nd][2] += xv.x * w0.z + xv.y * w1.z + xv.z * w2.z + xv.w * w3.z;
      acc[nd][3] += xv.x * w0.w + xv.y * w1.w + xv.z * w2.w + xv.w * w3.w;
    }
  }
  // epilogue: bf16 h2 store + fused alpha2 dots (32-lane half-wave reduce)
  float s0 = a_src[c4], s1 = a_src[c4 + 1], s2 = a_src[c4 + 2], s3 = a_src[c4 + 3];
  float d0 = a_dst[c4], d1 = a_dst[c4 + 1], d2 = a_dst[c4 + 2], d3 = a_dst[c4 + 3];
#pragma unroll
  for (int nd = 0; nd < 4; ++nd) {
    int n = nb + nrow0 + nd;
    float av = acc[nd][0] * s0 + acc[nd][1] * s1 + acc[nd][2] * s2 + acc[nd][3] * s3;
    float dv = acc[nd][0] * d0 + acc[nd][1] * d1 + acc[nd][2] * d2 + acc[nd][3] * d3;
#pragma unroll
    for (int o = 16; o > 0; o >>= 1) {
      av += __shfl_down(av, o, 32);
      dv += __shfl_down(dv, o, 32);
    }
    if (n < N) {
      ushort4 ob;
      ob.x = f2bf(acc[nd][0]);
      ob.y = f2bf(acc[nd][1]);
      ob.z = f2bf(acc[nd][2]);
      ob.w = f2bf(acc[nd][3]);
      *(ushort4*)(h2b + (size_t)n * HID + c4) = ob;
      if ((lane & 31) == 0) {
        asrc[n] = av;
        adst[n] = dv;
      }
    }
  }
}

extern "C" void kernel_launch(void* const* d_in, const int* in_sizes, int n_in,
                              void* d_out, int out_size, void* d_ws, size_t ws_size,
                              hipStream_t stream) {
  const float* x      = (const float*)d_in[0];
  const int*   ei     = (const int*)d_in[1];
  const float* W1     = (const float*)d_in[2];
  const float* a_src1 = (const float*)d_in[3];
  const float* a_dst1 = (const float*)d_in[4];
  const float* b1     = (const float*)d_in[5];
  const float* g1     = (const float*)d_in[6];
  const float* beta1  = (const float*)d_in[7];
  const float* W2     = (const float*)d_in[8];
  const float* a_src2 = (const float*)d_in[9];
  const float* a_dst2 = (const float*)d_in[10];
  const float* b2     = (const float*)d_in[11];
  const float* g2     = (const float*)d_in[12];
  const float* beta2  = (const float*)d_in[13];
  float* out = (float*)d_out;

  const int N = in_sizes[0] / IN_CH;
  const int E = in_sizes[1] / 2;
  const int Etot = E + N;
  const int nblk = (N + 255) / 256;

  // workspace layout
  unsigned short* hb  = (unsigned short*)d_ws;          // h1 bf16 -> h2 bf16
  unsigned short* x2b = hb + (size_t)N * HID;           // x2 bf16
  float* asrc1 = (float*)(x2b + (size_t)N * HID);
  float* adst1 = asrc1 + (size_t)N * HEADS;
  float* asrc2 = adst1 + (size_t)N * HEADS;
  float* adst2 = asrc2 + N;
  int* deg      = (int*)(adst2 + N);
  int* part     = deg + N;
  int* rowstart = part + N;           // [N+1]
  int* cursor   = rowstart + N + 1;
  int* aux      = cursor + N;         // [<=1024]
  int* csr_src  = aux + 1024;         // [Etot]

  // ---- CSR build (shared by both layers) ----
  hipMemsetAsync(deg, 0, (size_t)N * sizeof(int), stream);
  k_deg<<<(Etot + 255) / 256, 256, 0, stream>>>(ei, E, Etot, deg);
  k_scan1<<<nblk, 256, 0, stream>>>(deg, part, aux, N);
  k_scan2<<<1, 512, 0, stream>>>(aux, nblk);
  k_scan3<<<nblk, 256, 0, stream>>>(part, aux, rowstart, cursor, N, Etot);
  k_scatter<<<3584, 256, 0, stream>>>(ei, E, Etot, cursor, csr_src);

  // ---- Layer 1 ----
  k_gemm1<<<N, 128, 0, stream>>>(x, W1, a_src1, a_dst1, hb, asrc1, adst1, N);
  k_agg1<<<(N + 7) / 8, 256, 0, stream>>>(rowstart, csr_src, asrc1, adst1, hb,
                                          b1, g1, beta1, x2b, N);

  // ---- Layer 2 ----  (h2 bf16 reuses hb; h1 dead after agg1)
  k_gemm2f<<<(N + 31) / 32, 256, 0, stream>>>(x2b, W2, a_src2, a_dst2,
                                              hb, asrc2, adst2, N);
  k_agg2<<<(N + 7) / 8, 256, 0, stream>>>(rowstart, csr_src, asrc2, adst2, hb,
                                          b2, g2, beta2, out, N);
}